// Round 7
// baseline (817.325 us; speedup 1.0000x reference)
//
#include <hip/hip_runtime.h>
#include <hip/hip_fp16.h>
#include <math.h>

// Problem constants (match reference)
constexpr int N   = 16384;
constexpr int E   = 393216;
constexpr int G   = 256;
constexpr int HID = 128;
constexpr int SLOT = 64;       // padded CSR row capacity (max deg ~55 + self loop)

typedef _Float16 f16x8 __attribute__((ext_vector_type(8)));
typedef float    f32x4 __attribute__((ext_vector_type(4)));
typedef float    f32x2 __attribute__((ext_vector_type(2)));

// ---------------------------------------------------------------------------
// 16-lane (DPP row) all-lanes sum via row_ror 1,2,4,8 — pure VALU
// ---------------------------------------------------------------------------
__device__ __forceinline__ float red16(float x) {
    union fi { float f; int i; };
    fi a, b;
    a.f = x;
    b.i = __builtin_amdgcn_mov_dpp(a.i, 0x121, 0xf, 0xf, false); a.f += b.f;
    b.i = __builtin_amdgcn_mov_dpp(a.i, 0x122, 0xf, 0xf, false); a.f += b.f;
    b.i = __builtin_amdgcn_mov_dpp(a.i, 0x124, 0xf, 0xf, false); a.f += b.f;
    b.i = __builtin_amdgcn_mov_dpp(a.i, 0x128, 0xf, 0xf, false); a.f += b.f;
    return a.f;
}

// ---------------------------------------------------------------------------
// Packed-f32 VOP3P helpers (gfx90a+/CDNA4). One lane = one channel PAIR.
// _blo/_bhi broadcast the LO/HI dword of a wave-uniform SGPR pair into both
// halves via op_sel/op_sel_hi (DGEMM scalar-broadcast idiom).
// ---------------------------------------------------------------------------
__device__ __forceinline__ f32x2 pk_add(f32x2 a, f32x2 b) {
    f32x2 d;
    asm("v_pk_add_f32 %0, %1, %2" : "=v"(d) : "v"(a), "v"(b));
    return d;
}
__device__ __forceinline__ f32x2 pk_mul(f32x2 a, f32x2 b) {
    f32x2 d;
    asm("v_pk_mul_f32 %0, %1, %2" : "=v"(d) : "v"(a), "v"(b));
    return d;
}
__device__ __forceinline__ f32x2 pk_mul_bhi(f32x2 w, f32x2 s) {
    f32x2 d;  // both halves read HI dword of s
    asm("v_pk_mul_f32 %0, %1, %2 op_sel:[0,1] op_sel_hi:[1,1]"
        : "=v"(d) : "v"(w), "s"(s));
    return d;
}
__device__ __forceinline__ f32x2 pk_fma_blo(f32x2 w, f32x2 s, f32x2 c) {
    f32x2 d;  // both halves read LO dword of s
    asm("v_pk_fma_f32 %0, %1, %2, %3 op_sel:[0,0,0] op_sel_hi:[1,0,1]"
        : "=v"(d) : "v"(w), "s"(s), "v"(c));
    return d;
}
__device__ __forceinline__ f32x2 pk_fma_bhi(f32x2 w, f32x2 s, f32x2 c) {
    f32x2 d;  // both halves read HI dword of s
    asm("v_pk_fma_f32 %0, %1, %2, %3 op_sel:[0,1,0] op_sel_hi:[1,1,1]"
        : "=v"(d) : "v"(w), "s"(s), "v"(c));
    return d;
}

// ---------------------------------------------------------------------------
// R19: k_gemm_lr on MFMA (split-fp16)           -> 716.1 -> 677.4 µs
// R20/R21 FAILED: fp16 edge score math -> absmax 0.399. SCORE MATH STAYS FP32.
// R22: revert to f32 edge math; direct XL stores  -> 667.0 µs
// R23: k_edge packed-f32 VOP3P                    -> 659.0 µs (VALUBusy
//      65->58%, dur ~flat => k_edge latency-bound, TLP-covered)
// R24 FAILED: depth-2 pipeline (3-buffer)        -> 677.7 µs. VGPR 32->40,
//      occupancy 45->41%. With R5/R18: per-wave ILP deepening in k_edge is
//      STRUCTURALLY DEAD — TLP already covers the stall; extra buffers just
//      cost occupancy. k_edge floor with this structure ~43 µs.
// R25: revert k_edge loop to R23 depth-1 ping-pong (keep split FMA chains);
//      vectorize k_bnstats (float4 loads, 4x fewer VMEM insts) + k_scatter
//      (float2 edge_attr loads).
// Ledger of failed experiments (do not retry):
//   R3  float atomics into per-node sums       -> +100µs (atomic pipe bound)
//   R5  4 nodes/wave SERIAL                    -> occupancy collapse
//   R8  degree sorting                         -> broke L2 producer/consumer
//   R11-R13 non-scalar edge-loop bounds        -> VGPR 24->48; bounds MUST
//        be readfirstlane'd (ea loads must stay s_load)
//   R15 fused BN stats in 1024-thread shell    -> k_edge 45->59µs
//   R16 bnstats @1024 blocks + mixed prep      -> +143µs (same-address
//        atomic serialization; mixed dispatch runs at max of halves)
//   R18 2 nodes/wave interleaved               -> occupancy 47->35%
//   R20/21 fp16 score path                     -> absmax blowup
//   R24 3-buffer depth-2 prefetch              -> occupancy drop, +19µs
// ---------------------------------------------------------------------------
__global__ __launch_bounds__(256) void k_scatter(const int* __restrict__ src,
                                                 const int* __restrict__ dst,
                                                 int* __restrict__ fill,
                                                 const float* __restrict__ edge_attr,
                                                 int* __restrict__ csr_src,
                                                 float* __restrict__ csr_ea) {
    int e = blockIdx.x * 256 + threadIdx.x;
    if (e >= E) return;
    int d = dst[e];
    int pos = atomicAdd(&fill[d], 1);
    if (pos > 62) return;                  // defensive; never hit on this data
    size_t base = (size_t)d * SLOT + pos;
    csr_src[base] = src[e];
    const float2* s2 = (const float2*)(edge_attr + (size_t)e * 6);  // 8B-aligned
    float2 p0 = s2[0], p1 = s2[1], p2 = s2[2];
    float4 a = {p0.x, p0.y, p1.x, p1.y};
    float4 b = {p2.x, p2.y, 0.0f, 0.0f};
    float4* dstp = (float4*)(csr_ea + base * 8);
    dstp[0] = a;
    dstp[1] = b;
}

// Self-loop slot (at index deg): csr_src = node id, ea = mean of the row's
// real-edge attrs (read back from the contiguous padded row).
__global__ __launch_bounds__(256) void k_loopattr2(const int* __restrict__ fill,
                                                   int* __restrict__ csr_src,
                                                   float* __restrict__ csr_ea) {
    int i = blockIdx.x * 256 + threadIdx.x;
    if (i >= N) return;
    int deg = fill[i];
    deg = deg > 62 ? 62 : deg;
    size_t e0 = (size_t)i * SLOT;
    float4 sa = {0, 0, 0, 0};
    float sbx = 0.0f, sby = 0.0f;
    for (int e = 0; e < deg; e++) {
        const float4* p = (const float4*)(csr_ea + (e0 + e) * 8);
        float4 a = p[0];
        float4 b = p[1];
        sa.x += a.x; sa.y += a.y; sa.z += a.z; sa.w += a.w;
        sbx += b.x; sby += b.y;
    }
    float inv = 1.0f / fmaxf((float)deg, 1.0f);
    float4 oa = {sa.x * inv, sa.y * inv, sa.z * inv, sa.w * inv};
    float4 ob = {sbx * inv, sby * inv, 0.0f, 0.0f};
    float4* q = (float4*)(csr_ea + (e0 + deg) * 8);
    q[0] = oa;
    q[1] = ob;
    csr_src[e0 + deg] = i;
}

// ---------------------------------------------------------------------------
// Input projection: h = relu(x @ Win + b_in), x is (N,21)
// ---------------------------------------------------------------------------
__global__ __launch_bounds__(128) void k_ingemm(const float* __restrict__ x,
                                                const float* __restrict__ Win,
                                                const float* __restrict__ b_in,
                                                float* __restrict__ h) {
    __shared__ float xs[21];
    int i = blockIdx.x;
    int c = threadIdx.x;
    if (c < 21) xs[c] = x[i * 21 + c];
    __syncthreads();
    float acc = b_in[c];
#pragma unroll
    for (int d = 0; d < 21; d++) acc += xs[d] * Win[d * HID + c];
    h[i * HID + c] = fmaxf(acc, 0.0f);
}

// ---------------------------------------------------------------------------
// Weight prep (once): transposed split-fp16 planes WT[l][mat][{hi,lo}][col][k]
// so MFMA B-fragments (lane&15 = col, 8 contiguous k) are single 16B loads.
// ---------------------------------------------------------------------------
__global__ __launch_bounds__(128) void k_prepw(const float* __restrict__ Wl,
                                               const float* __restrict__ Wr,
                                               _Float16* __restrict__ WT) {
    int b = blockIdx.x;
    int col = b & 127;
    int mat = (b >> 7) & 1;
    int l = b >> 8;
    int k = threadIdx.x;
    const float* W = mat ? Wr : Wl;
    float w = W[((size_t)l * 128 + k) * 128 + col];
    _Float16 hi = (_Float16)w;
    _Float16 lo = (_Float16)(w - (float)hi);
    size_t base = ((size_t)(l * 2 + mat) * 2) << 14;   // *16384 halves
    WT[base + (size_t)col * 128 + k] = hi;
    WT[base + 16384 + (size_t)col * 128 + k] = lo;
}

// ---------------------------------------------------------------------------
// Per-layer projections on MFMA: XL = h@Wl + bl (stored FP16 -> 4MB,
// L2-resident), XR = h@Wr + br (fp32, exact). 32-row tile, 256 threads =
// 4 waves: waves 0/1 -> XL col halves; 2/3 -> XR. Split-fp16:
// D = Ahi*Whi + Alo*Whi + Ahi*Wlo in fp32 (err ~2^-22).
// ---------------------------------------------------------------------------
#define BN4(V, S, H) { V.x = fmaf(V.x, S.x, H.x); V.y = fmaf(V.y, S.y, H.y); \
                       V.z = fmaf(V.z, S.z, H.z); V.w = fmaf(V.w, S.w, H.w); }
#define ADD4(V, R)   { float4 _r = (R); V.x += _r.x; V.y += _r.y; \
                       V.z += _r.z; V.w += _r.w; }
#define RELU4(V)     { V.x = fmaxf(V.x, 0.f); V.y = fmaxf(V.y, 0.f); \
                       V.z = fmaxf(V.z, 0.f); V.w = fmaxf(V.w, 0.f); }
#define SPLIT(F, HIV, LOV, IDX) { float _f = (F); _Float16 _h = (_Float16)_f; \
                       HIV[IDX] = _h; LOV[IDX] = (_Float16)(_f - (float)_h); }

__global__ __launch_bounds__(256) void k_gemm_lr(const float* __restrict__ h,
                                                 const float* __restrict__ bns,
                                                 const float* __restrict__ gamma,
                                                 const float* __restrict__ beta,
                                                 float* __restrict__ res,
                                                 const _Float16* __restrict__ WT,
                                                 const float* __restrict__ bl,
                                                 const float* __restrict__ br,
                                                 __half* __restrict__ XLh,
                                                 float* __restrict__ XR) {
    __shared__ _Float16 hs_hi[32][136];
    __shared__ _Float16 hs_lo[32][136];
    __shared__ float sc[HID], sh[HID];
    int t = threadIdx.x;
    int r0 = blockIdx.x * 32;
    if (bns) {
        if (t < 128) {
            const float invN = 1.0f / (float)N;
            float mean = bns[t] * invN;
            float var  = bns[128 + t] * invN - mean * mean;
            float inv  = rsqrtf(var + 1e-5f);
            float s = gamma[t] * inv;
            sc[t] = s;
            sh[t] = beta[t] - mean * s;
        }
        __syncthreads();
    }
    {   // stage A-tile: BN-fuse (+residual) in fp32, split to hi/lo fp16 LDS
        int row = t >> 3;              // 0..31
        int cb  = (t & 7) * 16;        // 0,16,...,112
        size_t base = (size_t)(r0 + row) * HID + cb;
        const float4* srcp = (const float4*)&h[base];
        float4 v0 = srcp[0], v1 = srcp[1], v2 = srcp[2], v3 = srcp[3];
        if (bns) {
            float4 s0 = *(const float4*)&sc[cb];
            float4 s1 = *(const float4*)&sc[cb + 4];
            float4 s2 = *(const float4*)&sc[cb + 8];
            float4 s3 = *(const float4*)&sc[cb + 12];
            float4 h0 = *(const float4*)&sh[cb];
            float4 h1 = *(const float4*)&sh[cb + 4];
            float4 h2 = *(const float4*)&sh[cb + 8];
            float4 h3 = *(const float4*)&sh[cb + 12];
            BN4(v0, s0, h0); BN4(v1, s1, h1); BN4(v2, s2, h2); BN4(v3, s3, h3);
            if (res) {
                const float4* rp = (const float4*)&res[base];
                ADD4(v0, rp[0]); ADD4(v1, rp[1]); ADD4(v2, rp[2]); ADD4(v3, rp[3]);
            }
            RELU4(v0); RELU4(v1); RELU4(v2); RELU4(v3);
            if (res) {
                float4* wp = (float4*)&res[base];
                wp[0] = v0; wp[1] = v1; wp[2] = v2; wp[3] = v3;
            }
        }
        f16x8 hi0, hi1, lo0, lo1;
        SPLIT(v0.x, hi0, lo0, 0) SPLIT(v0.y, hi0, lo0, 1)
        SPLIT(v0.z, hi0, lo0, 2) SPLIT(v0.w, hi0, lo0, 3)
        SPLIT(v1.x, hi0, lo0, 4) SPLIT(v1.y, hi0, lo0, 5)
        SPLIT(v1.z, hi0, lo0, 6) SPLIT(v1.w, hi0, lo0, 7)
        SPLIT(v2.x, hi1, lo1, 0) SPLIT(v2.y, hi1, lo1, 1)
        SPLIT(v2.z, hi1, lo1, 2) SPLIT(v2.w, hi1, lo1, 3)
        SPLIT(v3.x, hi1, lo1, 4) SPLIT(v3.y, hi1, lo1, 5)
        SPLIT(v3.z, hi1, lo1, 6) SPLIT(v3.w, hi1, lo1, 7)
        *(f16x8*)&hs_hi[row][cb]     = hi0;
        *(f16x8*)&hs_hi[row][cb + 8] = hi1;
        *(f16x8*)&hs_lo[row][cb]     = lo0;
        *(f16x8*)&hs_lo[row][cb + 8] = lo1;
    }
    __syncthreads();

    int wv   = t >> 6;
    int lane = t & 63;
    int mat  = wv >> 1;            // 0 = L, 1 = R
    int ch   = wv & 1;             // column half of the 128 outputs
    int ln15 = lane & 15;
    int kg   = lane >> 4;          // k-group 0..3
    const _Float16* Whi = WT + ((size_t)mat * 2) * 16384;
    const float* bias = mat ? br : bl;
    f32x4 acc[2][4];
#pragma unroll
    for (int c = 0; c < 4; c++) {
        float bv = bias[(ch * 4 + c) * 16 + ln15];
        f32x4 b4 = {bv, bv, bv, bv};
        acc[0][c] = b4;
        acc[1][c] = b4;
    }
#pragma unroll
    for (int kt = 0; kt < 4; kt++) {
        int k0 = kt * 32 + kg * 8;
        f16x8 ahi0 = *(const f16x8*)&hs_hi[ln15][k0];
        f16x8 ahi1 = *(const f16x8*)&hs_hi[16 + ln15][k0];
        f16x8 alo0 = *(const f16x8*)&hs_lo[ln15][k0];
        f16x8 alo1 = *(const f16x8*)&hs_lo[16 + ln15][k0];
#pragma unroll
        for (int c = 0; c < 4; c++) {
            int col = (ch * 4 + c) * 16 + ln15;
            const _Float16* wp = Whi + (size_t)col * 128 + k0;
            f16x8 bhi = *(const f16x8*)wp;
            f16x8 blo = *(const f16x8*)(wp + 16384);
            acc[0][c] = __builtin_amdgcn_mfma_f32_16x16x32_f16(ahi0, bhi, acc[0][c], 0, 0, 0);
            acc[1][c] = __builtin_amdgcn_mfma_f32_16x16x32_f16(ahi1, bhi, acc[1][c], 0, 0, 0);
            acc[0][c] = __builtin_amdgcn_mfma_f32_16x16x32_f16(alo0, bhi, acc[0][c], 0, 0, 0);
            acc[1][c] = __builtin_amdgcn_mfma_f32_16x16x32_f16(alo1, bhi, acc[1][c], 0, 0, 0);
            acc[0][c] = __builtin_amdgcn_mfma_f32_16x16x32_f16(ahi0, blo, acc[0][c], 0, 0, 0);
            acc[1][c] = __builtin_amdgcn_mfma_f32_16x16x32_f16(ahi1, blo, acc[1][c], 0, 0, 0);
        }
    }
    // write out. D layout (verified m89): col = lane&15, row = (lane>>4)*4+reg
#pragma unroll
    for (int rt = 0; rt < 2; rt++) {
        int rowb = r0 + rt * 16 + kg * 4;
#pragma unroll
        for (int c = 0; c < 4; c++) {
            int col = (ch * 4 + c) * 16 + ln15;
            if (mat) {
#pragma unroll
                for (int r = 0; r < 4; r++)
                    XR[(size_t)(rowb + r) * 128 + col] = acc[rt][c][r];
            } else {
#pragma unroll
                for (int r = 0; r < 4; r++)
                    XLh[(size_t)(rowb + r) * 128 + col] = __float2half(acc[rt][c][r]);
            }
        }
    }
}

// ---------------------------------------------------------------------------
// Edge kernel (R23 structure, restored): 256-thread blocks = 4 waves, one
// node per wave. Node id readfirstlane'd -> addressing wave-uniform ->
// SGPRs + s_loads. Depth-1 ping-pong prefetch (idx 2 chunks ahead, xl+ea 1
// chunk ahead) — deeper pipelining is ledgered-dead (R24). Packed-f32
// message math with 2x3 split FMA chains; DPP reduce; exp2 on pre-scaled
// scores.
// ---------------------------------------------------------------------------
__global__ __launch_bounds__(256, 4) void k_edge(const int* __restrict__ fill,
                                                 const int* __restrict__ csr_src,
                                                 const float* __restrict__ csr_ea,
                                                 const __half2* __restrict__ xlh,
                                                 const float* __restrict__ xr,
                                                 const float* __restrict__ We_l,
                                                 const float* __restrict__ att_l,
                                                 float* __restrict__ gout) {
    int iv = (blockIdx.x * 256 + threadIdx.x) >> 6;    // node = global wave id
    int i = __builtin_amdgcn_readfirstlane(iv);        // -> SGPR (critical)
    int lane = threadIdx.x & 63;
    int hh = lane >> 4;
    int ss = lane & 15;
    int ch0 = hh * 32 + 2 * ss;

    const float LOG2E = 1.44269504088896f;
    float a0 = att_l[ch0] * LOG2E, a1 = att_l[ch0 + 1] * LOG2E;
    f32x2 wep[6];
#pragma unroll
    for (int d = 0; d < 6; d++) {
        float2 wv = *(const float2*)&We_l[d * HID + ch0];
        wep[d] = (f32x2){wv.x, wv.y};
    }
    const f32x2 c02 = {0.2f, 0.2f};

    float2 xr2 = *(const float2*)&xr[(size_t)i * HID + ch0];
    f32x2 xr2v = {xr2.x, xr2.y};
    float rd = 0.0f, acc0 = 0.0f, acc1 = 0.0f;
    int deg = __builtin_amdgcn_readfirstlane(fill[i]);
    deg = deg > 62 ? 62 : deg;
    int e0 = i * SLOT;                     // scalar (i is SGPR)
    int e1 = e0 + deg + 1;                 // + self loop
    int nedge = deg + 1;
    int nfull = nedge >> 2;
    int efull = e0 + (nfull << 2);

    auto ld_idx = [&](int e, int out[4]) {
#pragma unroll
        for (int k = 0; k < 4; k++) {
            int ec = e + k;
            ec = (ec < e1) ? ec : (e1 - 1);
            out[k] = __builtin_amdgcn_readfirstlane(csr_src[ec]);
        }
    };
    auto ld_xl = [&](const int idx[4], __half2 out[4]) {
#pragma unroll
        for (int k = 0; k < 4; k++)
            out[k] = xlh[(size_t)idx[k] * 64 + lane];
    };
    auto ld_ea = [&](int e, f32x2 oA[4], f32x2 oB[4], f32x2 oC[4]) {
#pragma unroll
        for (int k = 0; k < 4; k++) {
            const float* p = csr_ea + (size_t)(e + k) * 8;
            oA[k] = *(const f32x2*)p;
            oB[k] = *(const f32x2*)(p + 2);
            oC[k] = *(const f32x2*)(p + 4);
        }
    };
    auto edge1 = [&](__half2 xlv, f32x2 eA, f32x2 eB, f32x2 eC) -> float {
        float2 xf = __half22float2(xlv);
        f32x2 xf2 = {xf.x, xf.y};
        f32x2 m = pk_add(xf2, xr2v);        // chain 1 (4 deps)
        m = pk_fma_blo(wep[0], eA, m);
        m = pk_fma_bhi(wep[1], eA, m);
        m = pk_fma_blo(wep[2], eB, m);
        f32x2 tc = pk_mul_bhi(wep[3], eB);  // chain 2 (3 deps, parallel)
        tc = pk_fma_blo(wep[4], eC, tc);
        tc = pk_fma_bhi(wep[5], eC, tc);
        m = pk_add(m, tc);
        f32x2 tl = pk_mul(m, c02);
        float m0 = fmaxf(m[0], tl[0]);      // leaky relu
        float m1 = fmaxf(m[1], tl[1]);
        float pv = m0 * a0;
        pv = fmaf(m1, a1, pv);
        return red16(pv);                   // per-head score * log2e
    };
    auto bodyF = [&](const __half2 xlv[4], const f32x2 eA[4],
                     const f32x2 eB[4], const f32x2 eC[4]) {
#pragma unroll
        for (int k = 0; k < 4; k++) {
            float pv = edge1(xlv[k], eA[k], eB[k], eC[k]);
            float ex = exp2f(pv);
            rd += ex;
            float2 xf = __half22float2(xlv[k]);
            acc0 = fmaf(ex, xf.x, acc0);
            acc1 = fmaf(ex, xf.y, acc1);
        }
    };

    int iA[4], iB[4];
    __half2 x0[4], x1[4];
    f32x2 A0[4], B0[4], C0[4], A1[4], B1[4], C1[4];
    ld_idx(e0, iA);
    ld_idx(e0 + 4, iB);
    ld_xl(iA, x0);
    ld_ea(e0, A0, B0, C0);
    int e = e0, nf = nfull;
    while (nf >= 2) {
        ld_idx(e + 8, iA);                  // idx chunk n+2
        ld_xl(iB, x1);                      // data chunk n+1
        ld_ea(e + 4, A1, B1, C1);
        bodyF(x0, A0, B0, C0);              // compute chunk n
        ld_idx(e + 12, iB);                 // idx chunk n+3
        ld_xl(iA, x0);                      // data chunk n+2 (clamped idx; safe)
        ld_ea(e + 8, A0, B0, C0);           // may over-read into row pad: benign
        bodyF(x1, A1, B1, C1);              // compute chunk n+1
        e += 8; nf -= 2;
    }
    if (nf == 1) {
        bodyF(x0, A0, B0, C0);              // last full chunk
    }
    int rem = nedge & 3;
    if (rem) {                              // masked tail chunk at efull
        int it[4];
        __half2 xt[4];
        ld_idx(efull, it);
        ld_xl(it, xt);
#pragma unroll
        for (int k = 0; k < 4; k++) {
            int ee = efull + k;
            int ec = (ee < e1) ? ee : (e1 - 1);
            const float* p = csr_ea + (size_t)ec * 8;
            f32x2 eA = *(const f32x2*)p;
            f32x2 eB = *(const f32x2*)(p + 2);
            f32x2 eC = *(const f32x2*)(p + 4);
            float pv = edge1(xt[k], eA, eB, eC);
            pv = (ee < e1) ? pv : -INFINITY;
            float ex = exp2f(pv);
            rd += ex;
            float2 xf = __half22float2(xt[k]);
            acc0 = fmaf(ex, xf.x, acc0);
            acc1 = fmaf(ex, xf.y, acc1);
        }
    }
    float inv = 1.0f / rd;
    float2 o = {acc0 * inv, acc1 * inv};
    *(float2*)&gout[(size_t)i * HID + ch0] = o;
}

// ---------------------------------------------------------------------------
// BN statistics (R25: float4 loads — 16B/lane, one full row per wave-load;
// 4x fewer VMEM insts on the 8MB stream). 256 blocks x 256 threads; thread
// t owns channel quad (t&31)*4 over row group t>>5 (8 rows, stride 8).
// float4 LDS tree-reduce preserving t&31, then 256 atomics/block (the
// ledger-validated count; 1024/address was slower, R16).
// ---------------------------------------------------------------------------
__global__ __launch_bounds__(256) void k_bnstats(const float* __restrict__ v,
                                                 float* __restrict__ sums) {
    __shared__ float4 l_s[256], l_q[256];
    int t = threadIdx.x;
    int cq = (t & 31) * 4;         // channel quad
    int r  = blockIdx.x * 64 + (t >> 5);
    float4 s = {0, 0, 0, 0}, q = {0, 0, 0, 0};
#pragma unroll
    for (int it = 0; it < 8; it++, r += 8) {
        float4 val = *(const float4*)&v[(size_t)r * HID + cq];
        s.x += val.x; s.y += val.y; s.z += val.z; s.w += val.w;
        q.x = fmaf(val.x, val.x, q.x); q.y = fmaf(val.y, val.y, q.y);
        q.z = fmaf(val.z, val.z, q.z); q.w = fmaf(val.w, val.w, q.w);
    }
    l_s[t] = s; l_q[t] = q;
    __syncthreads();
    // halving reduce over row groups: t and t+stride share (t&31)
    if (t < 128) {
        float4 a = l_s[t], b = l_s[t + 128];
        a.x += b.x; a.y += b.y; a.z += b.z; a.w += b.w; l_s[t] = a;
        float4 c = l_q[t], d = l_q[t + 128];
        c.x += d.x; c.y += d.y; c.z += d.z; c.w += d.w; l_q[t] = c;
    }
    __syncthreads();
    if (t < 64) {
        float4 a = l_s[t], b = l_s[t + 64];
        a.x += b.x; a.y += b.y; a.z += b.z; a.w += b.w; l_s[t] = a;
        float4 c = l_q[t], d = l_q[t + 64];
        c.x += d.x; c.y += d.y; c.z += d.z; c.w += d.w; l_q[t] = c;
    }
    __syncthreads();
    if (t < 32) {
        float4 a = l_s[t], b = l_s[t + 32];
        a.x += b.x; a.y += b.y; a.z += b.z; a.w += b.w;
        atomicAdd(&sums[cq],     a.x);
        atomicAdd(&sums[cq + 1], a.y);
        atomicAdd(&sums[cq + 2], a.z);
        atomicAdd(&sums[cq + 3], a.w);
    } else if (t < 64) {
        int cq2 = ((t - 32) & 31) * 4;
        float4 c = l_q[t - 32], d = l_q[t];
        c.x += d.x; c.y += d.y; c.z += d.z; c.w += d.w;
        atomicAdd(&sums[128 + cq2],     c.x);
        atomicAdd(&sums[128 + cq2 + 1], c.y);
        atomicAdd(&sums[128 + cq2 + 2], c.z);
        atomicAdd(&sums[128 + cq2 + 3], c.w);
    }
}

// ---------------------------------------------------------------------------
// Pool per graph (batch is sorted) + MLP head. Fuses the final
// relu(BN(gout)+res) on the fly.
// ---------------------------------------------------------------------------
__global__ __launch_bounds__(128) void k_pool(const float* __restrict__ gout,
                                              const float* __restrict__ res,
                                              const float* __restrict__ bns,
                                              const float* __restrict__ gamma,
                                              const float* __restrict__ beta,
                                              const int* __restrict__ batch,
                                              const float* __restrict__ W1,
                                              const float* __restrict__ b1,
                                              const float* __restrict__ W2,
                                              const float* __restrict__ b2,
                                              float* __restrict__ out) {
    __shared__ float pooled[HID];
    __shared__ float hid[64];
    __shared__ int bounds[2];
    int g = blockIdx.x;
    int t = threadIdx.x;
    if (t < 2) {
        int target = g + t;
        int lo = 0, hi = N;
        while (lo < hi) {
            int mid = (lo + hi) >> 1;
            if (batch[mid] < target) lo = mid + 1; else hi = mid;
        }
        bounds[t] = lo;
    }
    const float invN = 1.0f / (float)N;
    float mean = bns[t] * invN;
    float var  = bns[128 + t] * invN - mean * mean;
    float scb  = gamma[t] * rsqrtf(var + 1e-5f);
    float shb  = beta[t] - mean * scb;
    __syncthreads();
    int s = bounds[0], e = bounds[1];
    float acc = 0.0f;
    for (int r = s; r < e; r++) {
        float v = fmaf(gout[(size_t)r * HID + t], scb, shb) + res[(size_t)r * HID + t];
        acc += fmaxf(v, 0.0f);
    }
    float cntf = fmaxf((float)(e - s), 1.0f);
    pooled[t] = acc / cntf;
    __syncthreads();
    if (t < 64) {
        float a = b1[t];
#pragma unroll 4
        for (int c = 0; c < HID; c++) a += pooled[c] * W1[c * 64 + t];
        hid[t] = fmaxf(a, 0.0f);
    }
    __syncthreads();
    if (t < 3) {
        float a = b2[t];
#pragma unroll
        for (int j = 0; j < 64; j++) a += hid[j] * W2[j * 3 + t];
        out[g * 3 + t] = a;
    }
}

// ---------------------------------------------------------------------------
// Launch
// ---------------------------------------------------------------------------
extern "C" void kernel_launch(void* const* d_in, const int* in_sizes, int n_in,
                              void* d_out, int out_size, void* d_ws, size_t ws_size,
                              hipStream_t stream) {
    const float* x         = (const float*)d_in[0];
    const int*   edge_index= (const int*)d_in[1];
    const float* edge_attr = (const float*)d_in[2];
    const int*   batch     = (const int*)d_in[3];
    const float* Win       = (const float*)d_in[4];
    const float* b_in      = (const float*)d_in[5];
    const float* Wl        = (const float*)d_in[6];
    const float* bl        = (const float*)d_in[7];
    const float* Wr        = (const float*)d_in[8];
    const float* br        = (const float*)d_in[9];
    const float* We        = (const float*)d_in[10];
    const float* att       = (const float*)d_in[11];
    const float* gamma     = (const float*)d_in[13];
    const float* beta      = (const float*)d_in[14];
    const float* W1        = (const float*)d_in[15];
    const float* b1        = (const float*)d_in[16];
    const float* W2        = (const float*)d_in[17];
    const float* b2        = (const float*)d_in[18];
    float* out = (float*)d_out;

    const int* src0 = edge_index;
    const int* dst0 = edge_index + E;

    char* ws = (char*)d_ws;
    size_t off = 0;
    auto alloc = [&](size_t bytes) -> void* {
        void* p = ws + off;
        off += (bytes + 255) & ~(size_t)255;
        return p;
    };
    // fill and bnsums contiguous: one memset covers both.
    int*      fill      = (int*)alloc((size_t)N * sizeof(int));
    float*    bnsums    = (float*)alloc((size_t)8 * 256 * sizeof(float));
    int*      csr_src   = (int*)alloc((size_t)N * SLOT * sizeof(int));
    float*    csr_ea    = (float*)alloc((size_t)N * SLOT * 8 * sizeof(float) + 512);
    float*    H0        = (float*)alloc((size_t)N * HID * sizeof(float));
    __half*   XLh       = (__half*)alloc((size_t)N * HID * sizeof(__half));
    float*    XR        = (float*)alloc((size_t)N * HID * sizeof(float));
    float*    GOUT      = (float*)alloc((size_t)N * HID * sizeof(float));
    _Float16* WT        = (_Float16*)alloc((size_t)8 * 4 * 16384 * 2);

    size_t zbytes = (size_t)N * sizeof(int) + 8 * 256 * sizeof(float);
    hipMemsetAsync(fill, 0, zbytes, stream);
    k_scatter<<<(E + 255) / 256, 256, 0, stream>>>(src0, dst0, fill,
                                                   edge_attr, csr_src, csr_ea);
    k_loopattr2<<<(N + 255) / 256, 256, 0, stream>>>(fill, csr_src, csr_ea);
    k_prepw<<<8 * 2 * 128, 128, 0, stream>>>(Wl, Wr, WT);
    k_ingemm<<<N, 128, 0, stream>>>(x, Win, b_in, H0);

    for (int l = 0; l < 8; l++) {
        bool odd = (l & 1) != 0;
        const float* hin;
        const float* bns_in = nullptr;
        const float* g_in = nullptr;
        const float* b_in2 = nullptr;
        float* res = nullptr;
        if (l == 0) {
            hin = H0;                       // plain load
        } else {
            hin = GOUT;                     // BN-fused load of previous GOUT
            bns_in = bnsums + (l - 1) * 256;
            g_in  = gamma + (size_t)(l - 1) * HID;
            b_in2 = beta  + (size_t)(l - 1) * HID;
            if (!odd) res = H0;             // even l>=2: +residual, writeback
        }
        k_gemm_lr<<<N / 32, 256, 0, stream>>>(hin, bns_in, g_in, b_in2, res,
                                              WT + (size_t)l * 4 * 16384,
                                              bl + l * HID, br + l * HID,
                                              XLh, XR);
        k_edge<<<N / 4, 256, 0, stream>>>(fill, csr_src, csr_ea,
                                          (const __half2*)XLh, XR,
                                          We + (size_t)l * 6 * HID,
                                          att + (size_t)l * HID, GOUT);
        k_bnstats<<<256, 256, 0, stream>>>(GOUT, bnsums + l * 256);
    }
    k_pool<<<G, 128, 0, stream>>>(GOUT, H0, bnsums + 7 * 256,
                                  gamma + 7 * HID, beta + 7 * HID,
                                  batch, W1, b1, W2, b2, out);
}

// Round 8
// 656.189 us; speedup vs baseline: 1.2456x; 1.2456x over previous
//
#include <hip/hip_runtime.h>
#include <hip/hip_fp16.h>
#include <math.h>

// Problem constants (match reference)
constexpr int N   = 16384;
constexpr int E   = 393216;
constexpr int G   = 256;
constexpr int HID = 128;
constexpr int SLOT = 64;       // padded CSR row capacity (max deg ~55 + self loop)

typedef _Float16 f16x8 __attribute__((ext_vector_type(8)));
typedef float    f32x4 __attribute__((ext_vector_type(4)));
typedef float    f32x2 __attribute__((ext_vector_type(2)));

// ---------------------------------------------------------------------------
// 16-lane (DPP row) all-lanes sum via row_ror 1,2,4,8 — pure VALU
// ---------------------------------------------------------------------------
__device__ __forceinline__ float red16(float x) {
    union fi { float f; int i; };
    fi a, b;
    a.f = x;
    b.i = __builtin_amdgcn_mov_dpp(a.i, 0x121, 0xf, 0xf, false); a.f += b.f;
    b.i = __builtin_amdgcn_mov_dpp(a.i, 0x122, 0xf, 0xf, false); a.f += b.f;
    b.i = __builtin_amdgcn_mov_dpp(a.i, 0x124, 0xf, 0xf, false); a.f += b.f;
    b.i = __builtin_amdgcn_mov_dpp(a.i, 0x128, 0xf, 0xf, false); a.f += b.f;
    return a.f;
}

// ---------------------------------------------------------------------------
// Packed-f32 VOP3P helpers (gfx90a+/CDNA4). One lane = one channel PAIR.
// _blo/_bhi broadcast the LO/HI dword of a wave-uniform SGPR pair into both
// halves via op_sel/op_sel_hi (DGEMM scalar-broadcast idiom).
// ---------------------------------------------------------------------------
__device__ __forceinline__ f32x2 pk_add(f32x2 a, f32x2 b) {
    f32x2 d;
    asm("v_pk_add_f32 %0, %1, %2" : "=v"(d) : "v"(a), "v"(b));
    return d;
}
__device__ __forceinline__ f32x2 pk_mul(f32x2 a, f32x2 b) {
    f32x2 d;
    asm("v_pk_mul_f32 %0, %1, %2" : "=v"(d) : "v"(a), "v"(b));
    return d;
}
__device__ __forceinline__ f32x2 pk_mul_bhi(f32x2 w, f32x2 s) {
    f32x2 d;  // both halves read HI dword of s
    asm("v_pk_mul_f32 %0, %1, %2 op_sel:[0,1] op_sel_hi:[1,1]"
        : "=v"(d) : "v"(w), "s"(s));
    return d;
}
__device__ __forceinline__ f32x2 pk_fma_blo(f32x2 w, f32x2 s, f32x2 c) {
    f32x2 d;  // both halves read LO dword of s
    asm("v_pk_fma_f32 %0, %1, %2, %3 op_sel:[0,0,0] op_sel_hi:[1,0,1]"
        : "=v"(d) : "v"(w), "s"(s), "v"(c));
    return d;
}
__device__ __forceinline__ f32x2 pk_fma_bhi(f32x2 w, f32x2 s, f32x2 c) {
    f32x2 d;  // both halves read HI dword of s
    asm("v_pk_fma_f32 %0, %1, %2, %3 op_sel:[0,1,0] op_sel_hi:[1,1,1]"
        : "=v"(d) : "v"(w), "s"(s), "v"(c));
    return d;
}

// ---------------------------------------------------------------------------
// R19: k_gemm_lr on MFMA (split-fp16)           -> 716.1 -> 677.4 µs
// R20/R21 FAILED: fp16 edge score math -> absmax 0.399. SCORE MATH STAYS FP32.
// R22: revert to f32 edge math; direct XL stores  -> 667.0 µs
// R23: k_edge packed-f32 VOP3P                    -> 659.0 µs (BASELINE)
// R24 FAILED: depth-2 pipeline -> occupancy drop  -> 677.7 µs
// R25 CONFOUNDED: bnstats-float4 + scatter-float2 -> 817 µs, but identical
//      k_edge code ran +7.6% slower (env contention, cold container). The
//      extra ~110µs unexplained — R25 changes reverted, NOT retried without
//      isolated A/B. R26 = exact R23 re-measure to re-establish baseline.
// Ledger of failed experiments (do not retry):
//   R3  float atomics into per-node sums       -> +100µs (atomic pipe bound)
//   R5  4 nodes/wave SERIAL                    -> occupancy collapse
//   R8  degree sorting                         -> broke L2 producer/consumer
//   R11-R13 non-scalar edge-loop bounds        -> VGPR 24->48; bounds MUST
//        be readfirstlane'd (ea loads must stay s_load)
//   R15 fused BN stats in 1024-thread shell    -> k_edge 45->59µs
//   R16 bnstats @1024 blocks + mixed prep      -> +143µs (same-address
//        atomic serialization; mixed dispatch runs at max of halves)
//   R18 2 nodes/wave interleaved               -> occupancy 47->35%
//   R20/21 fp16 score path                     -> absmax blowup
//   R24 3-buffer depth-2 prefetch              -> occupancy drop, +19µs
//   R25 bnstats float4 / scatter float2        -> confounded +158µs
// ---------------------------------------------------------------------------
__global__ __launch_bounds__(256) void k_scatter(const int* __restrict__ src,
                                                 const int* __restrict__ dst,
                                                 int* __restrict__ fill,
                                                 const float* __restrict__ edge_attr,
                                                 int* __restrict__ csr_src,
                                                 float* __restrict__ csr_ea) {
    int e = blockIdx.x * 256 + threadIdx.x;
    if (e >= E) return;
    int d = dst[e];
    int pos = atomicAdd(&fill[d], 1);
    if (pos > 62) return;                  // defensive; never hit on this data
    size_t base = (size_t)d * SLOT + pos;
    csr_src[base] = src[e];
    const float* s = edge_attr + (size_t)e * 6;
    float4 a = {s[0], s[1], s[2], s[3]};
    float4 b = {s[4], s[5], 0.0f, 0.0f};
    float4* dstp = (float4*)(csr_ea + base * 8);
    dstp[0] = a;
    dstp[1] = b;
}

// Self-loop slot (at index deg): csr_src = node id, ea = mean of the row's
// real-edge attrs (read back from the contiguous padded row).
__global__ __launch_bounds__(256) void k_loopattr2(const int* __restrict__ fill,
                                                   int* __restrict__ csr_src,
                                                   float* __restrict__ csr_ea) {
    int i = blockIdx.x * 256 + threadIdx.x;
    if (i >= N) return;
    int deg = fill[i];
    deg = deg > 62 ? 62 : deg;
    size_t e0 = (size_t)i * SLOT;
    float4 sa = {0, 0, 0, 0};
    float sbx = 0.0f, sby = 0.0f;
    for (int e = 0; e < deg; e++) {
        const float4* p = (const float4*)(csr_ea + (e0 + e) * 8);
        float4 a = p[0];
        float4 b = p[1];
        sa.x += a.x; sa.y += a.y; sa.z += a.z; sa.w += a.w;
        sbx += b.x; sby += b.y;
    }
    float inv = 1.0f / fmaxf((float)deg, 1.0f);
    float4 oa = {sa.x * inv, sa.y * inv, sa.z * inv, sa.w * inv};
    float4 ob = {sbx * inv, sby * inv, 0.0f, 0.0f};
    float4* q = (float4*)(csr_ea + (e0 + deg) * 8);
    q[0] = oa;
    q[1] = ob;
    csr_src[e0 + deg] = i;
}

// ---------------------------------------------------------------------------
// Input projection: h = relu(x @ Win + b_in), x is (N,21)
// ---------------------------------------------------------------------------
__global__ __launch_bounds__(128) void k_ingemm(const float* __restrict__ x,
                                                const float* __restrict__ Win,
                                                const float* __restrict__ b_in,
                                                float* __restrict__ h) {
    __shared__ float xs[21];
    int i = blockIdx.x;
    int c = threadIdx.x;
    if (c < 21) xs[c] = x[i * 21 + c];
    __syncthreads();
    float acc = b_in[c];
#pragma unroll
    for (int d = 0; d < 21; d++) acc += xs[d] * Win[d * HID + c];
    h[i * HID + c] = fmaxf(acc, 0.0f);
}

// ---------------------------------------------------------------------------
// Weight prep (once): transposed split-fp16 planes WT[l][mat][{hi,lo}][col][k]
// so MFMA B-fragments (lane&15 = col, 8 contiguous k) are single 16B loads.
// ---------------------------------------------------------------------------
__global__ __launch_bounds__(128) void k_prepw(const float* __restrict__ Wl,
                                               const float* __restrict__ Wr,
                                               _Float16* __restrict__ WT) {
    int b = blockIdx.x;
    int col = b & 127;
    int mat = (b >> 7) & 1;
    int l = b >> 8;
    int k = threadIdx.x;
    const float* W = mat ? Wr : Wl;
    float w = W[((size_t)l * 128 + k) * 128 + col];
    _Float16 hi = (_Float16)w;
    _Float16 lo = (_Float16)(w - (float)hi);
    size_t base = ((size_t)(l * 2 + mat) * 2) << 14;   // *16384 halves
    WT[base + (size_t)col * 128 + k] = hi;
    WT[base + 16384 + (size_t)col * 128 + k] = lo;
}

// ---------------------------------------------------------------------------
// Per-layer projections on MFMA: XL = h@Wl + bl (stored FP16 -> 4MB,
// L2-resident), XR = h@Wr + br (fp32, exact). 32-row tile, 256 threads =
// 4 waves: waves 0/1 -> XL col halves; 2/3 -> XR. Split-fp16:
// D = Ahi*Whi + Alo*Whi + Ahi*Wlo in fp32 (err ~2^-22).
// ---------------------------------------------------------------------------
#define BN4(V, S, H) { V.x = fmaf(V.x, S.x, H.x); V.y = fmaf(V.y, S.y, H.y); \
                       V.z = fmaf(V.z, S.z, H.z); V.w = fmaf(V.w, S.w, H.w); }
#define ADD4(V, R)   { float4 _r = (R); V.x += _r.x; V.y += _r.y; \
                       V.z += _r.z; V.w += _r.w; }
#define RELU4(V)     { V.x = fmaxf(V.x, 0.f); V.y = fmaxf(V.y, 0.f); \
                       V.z = fmaxf(V.z, 0.f); V.w = fmaxf(V.w, 0.f); }
#define SPLIT(F, HIV, LOV, IDX) { float _f = (F); _Float16 _h = (_Float16)_f; \
                       HIV[IDX] = _h; LOV[IDX] = (_Float16)(_f - (float)_h); }

__global__ __launch_bounds__(256) void k_gemm_lr(const float* __restrict__ h,
                                                 const float* __restrict__ bns,
                                                 const float* __restrict__ gamma,
                                                 const float* __restrict__ beta,
                                                 float* __restrict__ res,
                                                 const _Float16* __restrict__ WT,
                                                 const float* __restrict__ bl,
                                                 const float* __restrict__ br,
                                                 __half* __restrict__ XLh,
                                                 float* __restrict__ XR) {
    __shared__ _Float16 hs_hi[32][136];
    __shared__ _Float16 hs_lo[32][136];
    __shared__ float sc[HID], sh[HID];
    int t = threadIdx.x;
    int r0 = blockIdx.x * 32;
    if (bns) {
        if (t < 128) {
            const float invN = 1.0f / (float)N;
            float mean = bns[t] * invN;
            float var  = bns[128 + t] * invN - mean * mean;
            float inv  = rsqrtf(var + 1e-5f);
            float s = gamma[t] * inv;
            sc[t] = s;
            sh[t] = beta[t] - mean * s;
        }
        __syncthreads();
    }
    {   // stage A-tile: BN-fuse (+residual) in fp32, split to hi/lo fp16 LDS
        int row = t >> 3;              // 0..31
        int cb  = (t & 7) * 16;        // 0,16,...,112
        size_t base = (size_t)(r0 + row) * HID + cb;
        const float4* srcp = (const float4*)&h[base];
        float4 v0 = srcp[0], v1 = srcp[1], v2 = srcp[2], v3 = srcp[3];
        if (bns) {
            float4 s0 = *(const float4*)&sc[cb];
            float4 s1 = *(const float4*)&sc[cb + 4];
            float4 s2 = *(const float4*)&sc[cb + 8];
            float4 s3 = *(const float4*)&sc[cb + 12];
            float4 h0 = *(const float4*)&sh[cb];
            float4 h1 = *(const float4*)&sh[cb + 4];
            float4 h2 = *(const float4*)&sh[cb + 8];
            float4 h3 = *(const float4*)&sh[cb + 12];
            BN4(v0, s0, h0); BN4(v1, s1, h1); BN4(v2, s2, h2); BN4(v3, s3, h3);
            if (res) {
                const float4* rp = (const float4*)&res[base];
                ADD4(v0, rp[0]); ADD4(v1, rp[1]); ADD4(v2, rp[2]); ADD4(v3, rp[3]);
            }
            RELU4(v0); RELU4(v1); RELU4(v2); RELU4(v3);
            if (res) {
                float4* wp = (float4*)&res[base];
                wp[0] = v0; wp[1] = v1; wp[2] = v2; wp[3] = v3;
            }
        }
        f16x8 hi0, hi1, lo0, lo1;
        SPLIT(v0.x, hi0, lo0, 0) SPLIT(v0.y, hi0, lo0, 1)
        SPLIT(v0.z, hi0, lo0, 2) SPLIT(v0.w, hi0, lo0, 3)
        SPLIT(v1.x, hi0, lo0, 4) SPLIT(v1.y, hi0, lo0, 5)
        SPLIT(v1.z, hi0, lo0, 6) SPLIT(v1.w, hi0, lo0, 7)
        SPLIT(v2.x, hi1, lo1, 0) SPLIT(v2.y, hi1, lo1, 1)
        SPLIT(v2.z, hi1, lo1, 2) SPLIT(v2.w, hi1, lo1, 3)
        SPLIT(v3.x, hi1, lo1, 4) SPLIT(v3.y, hi1, lo1, 5)
        SPLIT(v3.z, hi1, lo1, 6) SPLIT(v3.w, hi1, lo1, 7)
        *(f16x8*)&hs_hi[row][cb]     = hi0;
        *(f16x8*)&hs_hi[row][cb + 8] = hi1;
        *(f16x8*)&hs_lo[row][cb]     = lo0;
        *(f16x8*)&hs_lo[row][cb + 8] = lo1;
    }
    __syncthreads();

    int wv   = t >> 6;
    int lane = t & 63;
    int mat  = wv >> 1;            // 0 = L, 1 = R
    int ch   = wv & 1;             // column half of the 128 outputs
    int ln15 = lane & 15;
    int kg   = lane >> 4;          // k-group 0..3
    const _Float16* Whi = WT + ((size_t)mat * 2) * 16384;
    const float* bias = mat ? br : bl;
    f32x4 acc[2][4];
#pragma unroll
    for (int c = 0; c < 4; c++) {
        float bv = bias[(ch * 4 + c) * 16 + ln15];
        f32x4 b4 = {bv, bv, bv, bv};
        acc[0][c] = b4;
        acc[1][c] = b4;
    }
#pragma unroll
    for (int kt = 0; kt < 4; kt++) {
        int k0 = kt * 32 + kg * 8;
        f16x8 ahi0 = *(const f16x8*)&hs_hi[ln15][k0];
        f16x8 ahi1 = *(const f16x8*)&hs_hi[16 + ln15][k0];
        f16x8 alo0 = *(const f16x8*)&hs_lo[ln15][k0];
        f16x8 alo1 = *(const f16x8*)&hs_lo[16 + ln15][k0];
#pragma unroll
        for (int c = 0; c < 4; c++) {
            int col = (ch * 4 + c) * 16 + ln15;
            const _Float16* wp = Whi + (size_t)col * 128 + k0;
            f16x8 bhi = *(const f16x8*)wp;
            f16x8 blo = *(const f16x8*)(wp + 16384);
            acc[0][c] = __builtin_amdgcn_mfma_f32_16x16x32_f16(ahi0, bhi, acc[0][c], 0, 0, 0);
            acc[1][c] = __builtin_amdgcn_mfma_f32_16x16x32_f16(ahi1, bhi, acc[1][c], 0, 0, 0);
            acc[0][c] = __builtin_amdgcn_mfma_f32_16x16x32_f16(alo0, bhi, acc[0][c], 0, 0, 0);
            acc[1][c] = __builtin_amdgcn_mfma_f32_16x16x32_f16(alo1, bhi, acc[1][c], 0, 0, 0);
            acc[0][c] = __builtin_amdgcn_mfma_f32_16x16x32_f16(ahi0, blo, acc[0][c], 0, 0, 0);
            acc[1][c] = __builtin_amdgcn_mfma_f32_16x16x32_f16(ahi1, blo, acc[1][c], 0, 0, 0);
        }
    }
    // write out. D layout (verified m89): col = lane&15, row = (lane>>4)*4+reg
#pragma unroll
    for (int rt = 0; rt < 2; rt++) {
        int rowb = r0 + rt * 16 + kg * 4;
#pragma unroll
        for (int c = 0; c < 4; c++) {
            int col = (ch * 4 + c) * 16 + ln15;
            if (mat) {
#pragma unroll
                for (int r = 0; r < 4; r++)
                    XR[(size_t)(rowb + r) * 128 + col] = acc[rt][c][r];
            } else {
#pragma unroll
                for (int r = 0; r < 4; r++)
                    XLh[(size_t)(rowb + r) * 128 + col] = __float2half(acc[rt][c][r]);
            }
        }
    }
}

// ---------------------------------------------------------------------------
// Edge kernel (R23 packed-f32): 256-thread blocks = 4 waves, one node per
// wave. Node id readfirstlane'd -> edge-loop addressing wave-uniform ->
// SGPRs + s_loads (ea as f32x2 SGPR pairs). Depth-1 ping-pong prefetch —
// deeper pipelining is ledgered-dead (R24). Per edge per lane: 1 pk_add,
// 6 pk_fma (ea broadcast from SGPR via op_sel), pk_mul + 2 max (leaky),
// 2 score ops, 4x(mov_dpp+add) reduce, exp2, 3 f32 accum.
// ---------------------------------------------------------------------------
__global__ __launch_bounds__(256, 4) void k_edge(const int* __restrict__ fill,
                                                 const int* __restrict__ csr_src,
                                                 const float* __restrict__ csr_ea,
                                                 const __half2* __restrict__ xlh,
                                                 const float* __restrict__ xr,
                                                 const float* __restrict__ We_l,
                                                 const float* __restrict__ att_l,
                                                 float* __restrict__ gout) {
    int iv = (blockIdx.x * 256 + threadIdx.x) >> 6;    // node = global wave id
    int i = __builtin_amdgcn_readfirstlane(iv);        // -> SGPR (critical)
    int lane = threadIdx.x & 63;
    int hh = lane >> 4;
    int ss = lane & 15;
    int ch0 = hh * 32 + 2 * ss;

    const float LOG2E = 1.44269504088896f;
    float a0 = att_l[ch0] * LOG2E, a1 = att_l[ch0 + 1] * LOG2E;
    f32x2 wep[6];
#pragma unroll
    for (int d = 0; d < 6; d++) {
        float2 wv = *(const float2*)&We_l[d * HID + ch0];
        wep[d] = (f32x2){wv.x, wv.y};
    }
    const f32x2 c02 = {0.2f, 0.2f};

    float2 xr2 = *(const float2*)&xr[(size_t)i * HID + ch0];
    f32x2 xr2v = {xr2.x, xr2.y};
    float rd = 0.0f, acc0 = 0.0f, acc1 = 0.0f;
    int deg = __builtin_amdgcn_readfirstlane(fill[i]);
    deg = deg > 62 ? 62 : deg;
    int e0 = i * SLOT;                     // scalar (i is SGPR)
    int e1 = e0 + deg + 1;                 // + self loop
    int nedge = deg + 1;
    int nfull = nedge >> 2;
    int efull = e0 + (nfull << 2);

    auto ld_idx = [&](int e, int out[4]) {
#pragma unroll
        for (int k = 0; k < 4; k++) {
            int ec = e + k;
            ec = (ec < e1) ? ec : (e1 - 1);
            out[k] = __builtin_amdgcn_readfirstlane(csr_src[ec]);
        }
    };
    auto ld_xl = [&](const int idx[4], __half2 out[4]) {
#pragma unroll
        for (int k = 0; k < 4; k++)
            out[k] = xlh[(size_t)idx[k] * 64 + lane];
    };
    auto ld_ea = [&](int e, f32x2 oA[4], f32x2 oB[4], f32x2 oC[4]) {
#pragma unroll
        for (int k = 0; k < 4; k++) {
            const float* p = csr_ea + (size_t)(e + k) * 8;
            oA[k] = *(const f32x2*)p;
            oB[k] = *(const f32x2*)(p + 2);
            oC[k] = *(const f32x2*)(p + 4);
        }
    };
    auto edge1 = [&](__half2 xlv, f32x2 eA, f32x2 eB, f32x2 eC) -> float {
        float2 xf = __half22float2(xlv);
        f32x2 xf2 = {xf.x, xf.y};
        f32x2 m = pk_add(xf2, xr2v);
        m = pk_fma_blo(wep[0], eA, m);
        m = pk_fma_bhi(wep[1], eA, m);
        m = pk_fma_blo(wep[2], eB, m);
        m = pk_fma_bhi(wep[3], eB, m);
        m = pk_fma_blo(wep[4], eC, m);
        m = pk_fma_bhi(wep[5], eC, m);
        f32x2 tl = pk_mul(m, c02);
        float m0 = fmaxf(m[0], tl[0]);      // leaky relu
        float m1 = fmaxf(m[1], tl[1]);
        float pv = m0 * a0;
        pv = fmaf(m1, a1, pv);
        return red16(pv);                   // per-head score * log2e
    };
    auto bodyF = [&](const __half2 xlv[4], const f32x2 eA[4],
                     const f32x2 eB[4], const f32x2 eC[4]) {
#pragma unroll
        for (int k = 0; k < 4; k++) {
            float pv = edge1(xlv[k], eA[k], eB[k], eC[k]);
            float ex = exp2f(pv);
            rd += ex;
            float2 xf = __half22float2(xlv[k]);
            acc0 = fmaf(ex, xf.x, acc0);
            acc1 = fmaf(ex, xf.y, acc1);
        }
    };

    int iA[4], iB[4];
    __half2 x0[4], x1[4];
    f32x2 A0[4], B0[4], C0[4], A1[4], B1[4], C1[4];
    ld_idx(e0, iA);
    ld_idx(e0 + 4, iB);
    ld_xl(iA, x0);
    ld_ea(e0, A0, B0, C0);
    int e = e0, nf = nfull;
    while (nf >= 2) {
        ld_idx(e + 8, iA);                  // idx chunk n+2
        ld_xl(iB, x1);                      // data chunk n+1
        ld_ea(e + 4, A1, B1, C1);
        bodyF(x0, A0, B0, C0);              // compute chunk n
        ld_idx(e + 12, iB);                 // idx chunk n+3
        ld_xl(iA, x0);                      // data chunk n+2 (clamped idx; safe)
        ld_ea(e + 8, A0, B0, C0);           // may over-read into row pad: benign
        bodyF(x1, A1, B1, C1);              // compute chunk n+1
        e += 8; nf -= 2;
    }
    if (nf == 1) {
        bodyF(x0, A0, B0, C0);              // last full chunk
    }
    int rem = nedge & 3;
    if (rem) {                              // masked tail chunk at efull
        int it[4];
        __half2 xt[4];
        ld_idx(efull, it);
        ld_xl(it, xt);
#pragma unroll
        for (int k = 0; k < 4; k++) {
            int ee = efull + k;
            int ec = (ee < e1) ? ee : (e1 - 1);
            const float* p = csr_ea + (size_t)ec * 8;
            f32x2 eA = *(const f32x2*)p;
            f32x2 eB = *(const f32x2*)(p + 2);
            f32x2 eC = *(const f32x2*)(p + 4);
            float pv = edge1(xt[k], eA, eB, eC);
            pv = (ee < e1) ? pv : -INFINITY;
            float ex = exp2f(pv);
            rd += ex;
            float2 xf = __half22float2(xt[k]);
            acc0 = fmaf(ex, xf.x, acc0);
            acc1 = fmaf(ex, xf.y, acc1);
        }
    }
    float inv = 1.0f / rd;
    float2 o = {acc0 * inv, acc1 * inv};
    *(float2*)&gout[(size_t)i * HID + ch0] = o;
}

// ---------------------------------------------------------------------------
// BN statistics over nodes (sum + sumsq per channel): 256 blocks, LDS
// pre-reduction, 256 atomics/block (65K/layer — safe; 1024/address was
// ~10µs/dispatch slower, R16).
// ---------------------------------------------------------------------------
__global__ __launch_bounds__(256) void k_bnstats(const float* __restrict__ v,
                                                 float* __restrict__ sums) {
    __shared__ float l_s[256], l_q[256];
    int t = threadIdx.x;
    int c = t & 127;
    int half = t >> 7;
    int r = blockIdx.x * 64 + half;
    float s = 0.0f, q = 0.0f;
    for (int it = 0; it < 32; it++, r += 2) {
        float val = v[(size_t)r * HID + c];
        s += val;
        q = fmaf(val, val, q);
    }
    l_s[t] = s; l_q[t] = q;
    __syncthreads();
    if (t < 128) {
        s = l_s[t] + l_s[t + 128];
        atomicAdd(&sums[c], s);
    } else {
        q = l_q[t] + l_q[t - 128];
        atomicAdd(&sums[128 + c], q);
    }
}

// ---------------------------------------------------------------------------
// Pool per graph (batch is sorted) + MLP head. Fuses the final
// relu(BN(gout)+res) on the fly.
// ---------------------------------------------------------------------------
__global__ __launch_bounds__(128) void k_pool(const float* __restrict__ gout,
                                              const float* __restrict__ res,
                                              const float* __restrict__ bns,
                                              const float* __restrict__ gamma,
                                              const float* __restrict__ beta,
                                              const int* __restrict__ batch,
                                              const float* __restrict__ W1,
                                              const float* __restrict__ b1,
                                              const float* __restrict__ W2,
                                              const float* __restrict__ b2,
                                              float* __restrict__ out) {
    __shared__ float pooled[HID];
    __shared__ float hid[64];
    __shared__ int bounds[2];
    int g = blockIdx.x;
    int t = threadIdx.x;
    if (t < 2) {
        int target = g + t;
        int lo = 0, hi = N;
        while (lo < hi) {
            int mid = (lo + hi) >> 1;
            if (batch[mid] < target) lo = mid + 1; else hi = mid;
        }
        bounds[t] = lo;
    }
    const float invN = 1.0f / (float)N;
    float mean = bns[t] * invN;
    float var  = bns[128 + t] * invN - mean * mean;
    float scb  = gamma[t] * rsqrtf(var + 1e-5f);
    float shb  = beta[t] - mean * scb;
    __syncthreads();
    int s = bounds[0], e = bounds[1];
    float acc = 0.0f;
    for (int r = s; r < e; r++) {
        float v = fmaf(gout[(size_t)r * HID + t], scb, shb) + res[(size_t)r * HID + t];
        acc += fmaxf(v, 0.0f);
    }
    float cntf = fmaxf((float)(e - s), 1.0f);
    pooled[t] = acc / cntf;
    __syncthreads();
    if (t < 64) {
        float a = b1[t];
#pragma unroll 4
        for (int c = 0; c < HID; c++) a += pooled[c] * W1[c * 64 + t];
        hid[t] = fmaxf(a, 0.0f);
    }
    __syncthreads();
    if (t < 3) {
        float a = b2[t];
#pragma unroll
        for (int j = 0; j < 64; j++) a += hid[j] * W2[j * 3 + t];
        out[g * 3 + t] = a;
    }
}

// ---------------------------------------------------------------------------
// Launch
// ---------------------------------------------------------------------------
extern "C" void kernel_launch(void* const* d_in, const int* in_sizes, int n_in,
                              void* d_out, int out_size, void* d_ws, size_t ws_size,
                              hipStream_t stream) {
    const float* x         = (const float*)d_in[0];
    const int*   edge_index= (const int*)d_in[1];
    const float* edge_attr = (const float*)d_in[2];
    const int*   batch     = (const int*)d_in[3];
    const float* Win       = (const float*)d_in[4];
    const float* b_in      = (const float*)d_in[5];
    const float* Wl        = (const float*)d_in[6];
    const float* bl        = (const float*)d_in[7];
    const float* Wr        = (const float*)d_in[8];
    const float* br        = (const float*)d_in[9];
    const float* We        = (const float*)d_in[10];
    const float* att       = (const float*)d_in[11];
    const float* gamma     = (const float*)d_in[13];
    const float* beta      = (const float*)d_in[14];
    const float* W1        = (const float*)d_in[15];
    const float* b1        = (const float*)d_in[16];
    const float* W2        = (const float*)d_in[17];
    const float* b2        = (const float*)d_in[18];
    float* out = (float*)d_out;

    const int* src0 = edge_index;
    const int* dst0 = edge_index + E;

    char* ws = (char*)d_ws;
    size_t off = 0;
    auto alloc = [&](size_t bytes) -> void* {
        void* p = ws + off;
        off += (bytes + 255) & ~(size_t)255;
        return p;
    };
    // fill and bnsums contiguous: one memset covers both.
    int*      fill      = (int*)alloc((size_t)N * sizeof(int));
    float*    bnsums    = (float*)alloc((size_t)8 * 256 * sizeof(float));
    int*      csr_src   = (int*)alloc((size_t)N * SLOT * sizeof(int));
    float*    csr_ea    = (float*)alloc((size_t)N * SLOT * 8 * sizeof(float) + 512);
    float*    H0        = (float*)alloc((size_t)N * HID * sizeof(float));
    __half*   XLh       = (__half*)alloc((size_t)N * HID * sizeof(__half));
    float*    XR        = (float*)alloc((size_t)N * HID * sizeof(float));
    float*    GOUT      = (float*)alloc((size_t)N * HID * sizeof(float));
    _Float16* WT        = (_Float16*)alloc((size_t)8 * 4 * 16384 * 2);

    size_t zbytes = (size_t)N * sizeof(int) + 8 * 256 * sizeof(float);
    hipMemsetAsync(fill, 0, zbytes, stream);
    k_scatter<<<(E + 255) / 256, 256, 0, stream>>>(src0, dst0, fill,
                                                   edge_attr, csr_src, csr_ea);
    k_loopattr2<<<(N + 255) / 256, 256, 0, stream>>>(fill, csr_src, csr_ea);
    k_prepw<<<8 * 2 * 128, 128, 0, stream>>>(Wl, Wr, WT);
    k_ingemm<<<N, 128, 0, stream>>>(x, Win, b_in, H0);

    for (int l = 0; l < 8; l++) {
        bool odd = (l & 1) != 0;
        const float* hin;
        const float* bns_in = nullptr;
        const float* g_in = nullptr;
        const float* b_in2 = nullptr;
        float* res = nullptr;
        if (l == 0) {
            hin = H0;                       // plain load
        } else {
            hin = GOUT;                     // BN-fused load of previous GOUT
            bns_in = bnsums + (l - 1) * 256;
            g_in  = gamma + (size_t)(l - 1) * HID;
            b_in2 = beta  + (size_t)(l - 1) * HID;
            if (!odd) res = H0;             // even l>=2: +residual, writeback
        }
        k_gemm_lr<<<N / 32, 256, 0, stream>>>(hin, bns_in, g_in, b_in2, res,
                                              WT + (size_t)l * 4 * 16384,
                                              bl + l * HID, br + l * HID,
                                              XLh, XR);
        k_edge<<<N / 4, 256, 0, stream>>>(fill, csr_src, csr_ea,
                                          (const __half2*)XLh, XR,
                                          We + (size_t)l * 6 * HID,
                                          att + (size_t)l * HID, GOUT);
        k_bnstats<<<256, 256, 0, stream>>>(GOUT, bnsums + l * 256);
    }
    k_pool<<<G, 128, 0, stream>>>(GOUT, H0, bnsums + 7 * 256,
                                  gamma + 7 * HID, beta + 7 * HID,
                                  batch, W1, b1, W2, b2, out);
}